// Round 7
// baseline (360.014 us; speedup 1.0000x reference)
//
#include <hip/hip_runtime.h>
#include <stdint.h>

#define LOG2_HASHMAP_SIZE 19
#define HASHMAP_SIZE (1u << LOG2_HASHMAP_SIZE)
#define HASHMAP_MASK (HASHMAP_SIZE - 1u)
#define N_LEVELS 4

// Per-level fragment: loads land here (issue phase), math happens later
// (resolve phase) so many gathers stay in flight per thread.
struct LevelFrag {
    float4 v[4];   // per (y,z) combo: packed embeddings of both x-corners
    float  W[4];   // yz-weight per combo
    float  wl[4];  // weight multiplying v.xy
    float  wh[4];  // weight multiplying v.zw
};

__device__ __forceinline__ void level_issue(
    float px, float py, float pz,
    const float* __restrict__ tables, int li, float r, LevelFrag& F)
{
    const uint32_t P1 = 11614769u;
    const uint32_t P2 = 2654435761u;

    const float sx = px * r, sy = py * r, sz = pz * r;
    const float bx = floorf(sx), by = floorf(sy), bz = floorf(sz);
    const float tx = sx - bx, ty = sy - by, tz = sz - bz;
    const float ux = 1.0f - tx, uy = 1.0f - ty, uz = 1.0f - tz;

    const uint32_t ix = (uint32_t)(int)bx;
    const uint32_t iy = (uint32_t)(int)by;
    const uint32_t iz = (uint32_t)(int)bz;

    const uint32_t hy0 = iy * P1, hy1 = (iy + 1u) * P1;
    const uint32_t hz0 = iz * P2, hz1 = (iz + 1u) * P2;

    uint32_t S[4];
    S[0] = hy0 ^ hz0;  F.W[0] = uy * uz;
    S[1] = hy0 ^ hz1;  F.W[1] = uy * tz;
    S[2] = hy1 ^ hz0;  F.W[2] = ty * uz;
    S[3] = hy1 ^ hz1;  F.W[3] = ty * tz;

    const float* tab = tables + (size_t)li * HASHMAP_SIZE * 2;
    const float2* __restrict__ tab2 = (const float2*)tab;
    const float4* __restrict__ tab4 = (const float4*)tab;

    if ((ix & 1u) == 0u) {
        // even ix: x-corner pair {ix,ix+1} -> aligned table pair, one float4.
        // bit0(h0) = bit0(S[c]) (ix even) decides which half is corner 0;
        // select WEIGHTS by that bit (no dependency on loaded data).
        #pragma unroll
        for (int c = 0; c < 4; ++c) {
            const uint32_t h0 = (ix ^ S[c]) & HASHMAP_MASK;
            F.v[c] = tab4[h0 >> 1];
            const bool hi = (S[c] & 1u) != 0u;
            F.wl[c] = hi ? tx : ux;
            F.wh[c] = hi ? ux : tx;
        }
    } else {
        // odd ix: two float2 gathers per combo, packed into v halves.
        #pragma unroll
        for (int c = 0; c < 4; ++c) {
            const uint32_t h0 = (ix ^ S[c]) & HASHMAP_MASK;
            const uint32_t h1 = ((ix + 1u) ^ S[c]) & HASHMAP_MASK;
            ((float2*)&F.v[c])[0] = tab2[h0];
            ((float2*)&F.v[c])[1] = tab2[h1];
            F.wl[c] = ux;
            F.wh[c] = tx;
        }
    }
}

__device__ __forceinline__ float2 level_resolve(const LevelFrag& F)
{
    float f0 = 0.0f, f1 = 0.0f;
    #pragma unroll
    for (int c = 0; c < 4; ++c) {
        f0 += F.W[c] * (F.wl[c] * F.v[c].x + F.wh[c] * F.v[c].z);
        f1 += F.W[c] * (F.wl[c] * F.v[c].y + F.wh[c] * F.v[c].w);
    }
    return make_float2(f0, f1);
}

// Passes 0..2: 2 points per thread, both points' loads in flight together.
__global__ __launch_bounds__(256) void pass_ws_kernel(
    const float* __restrict__ x, const float* __restrict__ tables,
    float2* __restrict__ ws, int li, float r, int n)
{
    const int t = blockIdx.x * blockDim.x + threadIdx.x;
    const int i0 = 2 * t;
    if (i0 >= n) return;
    const bool two = (i0 + 1 < n);

    float pxA, pyA, pzA, pxB, pyB, pzB;
    if (two) {
        const float2* __restrict__ x2 = (const float2*)x;
        const float2 q0 = x2[3 * (size_t)t + 0];
        const float2 q1 = x2[3 * (size_t)t + 1];
        const float2 q2 = x2[3 * (size_t)t + 2];
        pxA = q0.x; pyA = q0.y; pzA = q1.x;
        pxB = q1.y; pyB = q2.x; pzB = q2.y;
    } else {
        pxA = x[3 * (size_t)i0 + 0];
        pyA = x[3 * (size_t)i0 + 1];
        pzA = x[3 * (size_t)i0 + 2];
        pxB = pxA; pyB = pyA; pzB = pzA;
    }

    LevelFrag FA, FB;
    level_issue(pxA, pyA, pzA, tables, li, r, FA);
    level_issue(pxB, pyB, pzB, tables, li, r, FB);
    const float2 rA = level_resolve(FA);
    const float2 rB = level_resolve(FB);
    ws[i0] = rA;
    if (two) ws[i0 + 1] = rB;
}

// Final pass: level 3 (2 points/thread) + combine with ws levels 0..2.
__global__ __launch_bounds__(256) void final_kernel(
    const float* __restrict__ x, const float* __restrict__ tables,
    const float2* __restrict__ ws0, const float2* __restrict__ ws1,
    const float2* __restrict__ ws2, float* __restrict__ out, int n)
{
    const int t = blockIdx.x * blockDim.x + threadIdx.x;
    const int i0 = 2 * t;
    if (i0 >= n) return;
    const bool two = (i0 + 1 < n);

    float pxA, pyA, pzA, pxB, pyB, pzB;
    if (two) {
        const float2* __restrict__ x2 = (const float2*)x;
        const float2 q0 = x2[3 * (size_t)t + 0];
        const float2 q1 = x2[3 * (size_t)t + 1];
        const float2 q2 = x2[3 * (size_t)t + 2];
        pxA = q0.x; pyA = q0.y; pzA = q1.x;
        pxB = q1.y; pyB = q2.x; pzB = q2.y;
    } else {
        pxA = x[3 * (size_t)i0 + 0];
        pyA = x[3 * (size_t)i0 + 1];
        pzA = x[3 * (size_t)i0 + 2];
        pxB = pxA; pyB = pyA; pzB = pzA;
    }

    LevelFrag FA, FB;
    level_issue(pxA, pyA, pzA, tables, 3, 512.0f, FA);
    level_issue(pxB, pyB, pzB, tables, 3, 512.0f, FB);

    const float2 a0 = ws0[i0];
    const float2 a1 = ws1[i0];
    const float2 a2 = ws2[i0];
    const int iB = two ? (i0 + 1) : i0;
    const float2 b0 = ws0[iB];
    const float2 b1 = ws1[iB];
    const float2 b2 = ws2[iB];

    const float2 a3 = level_resolve(FA);
    const float2 b3 = level_resolve(FB);

    float4* opA = (float4*)(out + 8 * (size_t)i0);
    opA[0] = make_float4(a0.x, a0.y, a1.x, a1.y);
    opA[1] = make_float4(a2.x, a2.y, a3.x, a3.y);
    if (two) {
        float4* opB = (float4*)(out + 8 * (size_t)(i0 + 1));
        opB[0] = make_float4(b0.x, b0.y, b1.x, b1.y);
        opB[1] = make_float4(b2.x, b2.y, b3.x, b3.y);
    }
}

// Fallback (ws too small): per-level pass writing strided into out directly.
__global__ __launch_bounds__(256) void pass_direct_kernel(
    const float* __restrict__ x, const float* __restrict__ tables,
    float* __restrict__ out, int li, float r, int n)
{
    const int i = blockIdx.x * blockDim.x + threadIdx.x;
    if (i >= n) return;
    const float px = x[3 * (size_t)i + 0];
    const float py = x[3 * (size_t)i + 1];
    const float pz = x[3 * (size_t)i + 2];
    LevelFrag F;
    level_issue(px, py, pz, tables, li, r, F);
    const float2 e = level_resolve(F);
    float2* op = (float2*)(out + 8 * (size_t)i + 2 * li);
    *op = e;
}

extern "C" void kernel_launch(void* const* d_in, const int* in_sizes, int n_in,
                              void* d_out, int out_size, void* d_ws, size_t ws_size,
                              hipStream_t stream) {
    const float* x = (const float*)d_in[0];        // [N, 3]
    const float* tables = (const float*)d_in[1];   // [4, 2^19, 2]
    float* out = (float*)d_out;                    // [N, 8]
    const int n = in_sizes[0] / 3;

    const float res[N_LEVELS] = {30.0f, 80.0f, 210.0f, 512.0f};
    const int block = 256;
    const int grid2 = ((n + 1) / 2 + block - 1) / block;   // 2 points/thread

    const size_t ws_needed = 3 * (size_t)n * sizeof(float2);
    if (ws_size >= ws_needed) {
        float2* ws = (float2*)d_ws;
        for (int li = 0; li < 3; ++li) {
            pass_ws_kernel<<<grid2, block, 0, stream>>>(
                x, tables, ws + (size_t)li * n, li, res[li], n);
        }
        final_kernel<<<grid2, block, 0, stream>>>(
            x, tables, ws, ws + (size_t)n, ws + 2 * (size_t)n, out, n);
    } else {
        const int grid = (n + block - 1) / block;
        for (int li = 0; li < N_LEVELS; ++li) {
            pass_direct_kernel<<<grid, block, 0, stream>>>(
                x, tables, out, li, res[li], n);
        }
    }
}